// Round 1
// baseline (88.902 us; speedup 1.0000x reference)
//
#include <hip/hip_runtime.h>
#include <math.h>

#define B_ 8
#define N_ 128
#define L_ 30
#define D_ 256
#define NEGV -1000000000.0f
#define SCALE 0.0625f   // 1/sqrt(256)
#define ROWS 8
#define NR 16

// ---------------- Kernel 1: k = f_w @ Wk^T + bk  (B*L rows) ----------------
__global__ __launch_bounds__(256) void k_proj(const float* __restrict__ f_w,
    const float* __restrict__ Wk, const float* __restrict__ bk,
    float* __restrict__ k_out) {
  int bl = blockIdx.x;          // b*L + l
  int d  = threadIdx.x;         // 0..255
  __shared__ float fw[D_];
  fw[d] = f_w[bl * D_ + d];
  __syncthreads();
  const float4* wrow = (const float4*)(Wk + (size_t)d * D_);
  float acc = 0.f;
#pragma unroll 8
  for (int j = 0; j < D_ / 4; ++j) {
    float4 w = wrow[j];
    acc += w.x * fw[4*j+0] + w.y * fw[4*j+1] + w.z * fw[4*j+2] + w.w * fw[4*j+3];
  }
  k_out[bl * D_ + d] = acc + bk[d];
}

// ---- Kernel 2: q-proj + aw softmax (over L) + f_baq + f_bq, 8 n-rows/block ----
__global__ __launch_bounds__(256) void qk_fbq(const float* __restrict__ f_b,
    const float* __restrict__ f_w, const float* __restrict__ f_s,
    const float* __restrict__ qmask, const float* __restrict__ lmask,
    const float* __restrict__ Wq, const float* __restrict__ bq,
    const float* __restrict__ kmat, float* __restrict__ f_bq) {
  int blk = blockIdx.x;
  int b   = blk / (N_ / ROWS);
  int n0  = (blk % (N_ / ROWS)) * ROWS;
  int d   = threadIdx.x;

  __shared__ float fb[ROWS][D_];        // broadcast reads only
  __shared__ float qs[ROWS][D_ + 1];    // padded
  __shared__ float aw[ROWS][L_ + 2];

  for (int r = 0; r < ROWS; ++r)
    fb[r][d] = f_b[(size_t)(b * N_ + n0 + r) * D_ + d];
  __syncthreads();

  // q[r][d] = f_b[r] . Wq[d,:] + bq[d]
  float qacc[ROWS];
#pragma unroll
  for (int r = 0; r < ROWS; ++r) qacc[r] = 0.f;
  const float4* wrow = (const float4*)(Wq + (size_t)d * D_);
  for (int j = 0; j < D_ / 4; ++j) {
    float4 w = wrow[j];
#pragma unroll
    for (int r = 0; r < ROWS; ++r)
      qacc[r] += w.x*fb[r][4*j] + w.y*fb[r][4*j+1] + w.z*fb[r][4*j+2] + w.w*fb[r][4*j+3];
  }
  float bqd = bq[d];
#pragma unroll
  for (int r = 0; r < ROWS; ++r) qs[r][d] = qacc[r] + bqd;
  __syncthreads();

  // aw[r][l] = (q[r] . k[l]) * scale, with query mask
  if (d < ROWS * L_) {
    int r = d / L_, l = d % L_;
    const float4* krow = (const float4*)(kmat + (size_t)(b * L_ + l) * D_);
    float acc = 0.f;
    for (int j = 0; j < D_ / 4; ++j) {
      float4 kv = krow[j];
      acc += kv.x*qs[r][4*j] + kv.y*qs[r][4*j+1] + kv.z*qs[r][4*j+2] + kv.w*qs[r][4*j+3];
    }
    float qm = qmask[b * L_ + l];
    aw[r][l] = (qm == 0.f) ? NEGV : acc * SCALE * qm;
  }
  __syncthreads();

  // per-row softmax over L=30 (serial, 8 threads — tiny)
  if (d < ROWS) {
    int r = d;
    float mx = -1e30f;
    for (int l = 0; l < L_; ++l) mx = fmaxf(mx, aw[r][l]);
    float s = 0.f;
    for (int l = 0; l < L_; ++l) { float e = __expf(aw[r][l] - mx); aw[r][l] = e; s += e; }
    float inv = 1.f / s;
    for (int l = 0; l < L_; ++l) aw[r][l] *= inv;
  }
  __syncthreads();

  // f_baq[r][d] = sum_l aw[r][l] * f_w[l][d];  f_bq = f_b * (f_baq*lm + f_s)
  float facc[ROWS];
#pragma unroll
  for (int r = 0; r < ROWS; ++r) facc[r] = 0.f;
  for (int l = 0; l < L_; ++l) {
    float fwv = f_w[(size_t)(b * L_ + l) * D_ + d];
#pragma unroll
    for (int r = 0; r < ROWS; ++r) facc[r] += aw[r][l] * fwv;
  }
  float fsd = f_s[b * D_ + d];
  for (int r = 0; r < ROWS; ++r) {
    float lm = lmask[b * N_ + n0 + r];
    f_bq[(size_t)(b * N_ + n0 + r) * D_ + d] = fb[r][d] * (facc[r] * lm + fsd);
  }
}

// ---- Kernel 3: A' = softmax(f_bq f_bq^T * scale, masked) * fb_mask ----
__global__ __launch_bounds__(256) void a_soft(const float* __restrict__ f_bq,
    const float* __restrict__ lmask, float* __restrict__ Amat) {
  int b  = blockIdx.x / (N_ / NR);
  int n0 = (blockIdx.x % (N_ / NR)) * NR;
  int t  = threadIdx.x;
  int m_local = t & 31;
  int r = t >> 5;   // 0..7 ; handles rows r and r+8

  __shared__ float qrows[NR][D_ + 1];
  __shared__ float chunk[32][D_ + 1];

  for (int rr = 0; rr < NR; ++rr)
    qrows[rr][t] = f_bq[(size_t)(b * N_ + n0 + rr) * D_ + t];

  float av[2][4];
#pragma unroll
  for (int i = 0; i < 2; ++i)
#pragma unroll
    for (int c = 0; c < 4; ++c) av[i][c] = 0.f;

  for (int c = 0; c < 4; ++c) {
    __syncthreads();
    for (int i = 0; i < 32; ++i)
      chunk[i][t] = f_bq[(size_t)(b * N_ + c * 32 + i) * D_ + t];
    __syncthreads();
    float a0 = 0.f, a1 = 0.f;
    for (int dd = 0; dd < D_; ++dd) {
      float cv = chunk[m_local][dd];
      a0 += qrows[r][dd] * cv;
      a1 += qrows[r + 8][dd] * cv;
    }
    av[0][c] = a0; av[1][c] = a1;
  }

#pragma unroll
  for (int i = 0; i < 2; ++i) {
    int n = n0 + r + i * 8;
    float vals[4];
    float mx = -1e30f;
#pragma unroll
    for (int c = 0; c < 4; ++c) {
      int m = c * 32 + m_local;
      float lm = lmask[b * N_ + m];
      float x = (lm == 0.f) ? NEGV : av[i][c] * SCALE * lm;
      vals[c] = x; mx = fmaxf(mx, x);
    }
#pragma unroll
    for (int off = 16; off >= 1; off >>= 1) mx = fmaxf(mx, __shfl_xor(mx, off));
    float s = 0.f;
#pragma unroll
    for (int c = 0; c < 4; ++c) { vals[c] = __expf(vals[c] - mx); s += vals[c]; }
#pragma unroll
    for (int off = 16; off >= 1; off >>= 1) s += __shfl_xor(s, off);
    float fbm = lmask[b * N_ + n];
    float inv = fbm / s;
#pragma unroll
    for (int c = 0; c < 4; ++c)
      Amat[(size_t)(b * N_ + n) * N_ + c * 32 + m_local] = vals[c] * inv;
  }
}

// ---- Kernel 4 (dominant): out = f_b[n] + sum_m A'[n,m]*(f_b[m] + sig(fm*fs)*fm) ----
__global__ __launch_bounds__(256) void final_k(const float* __restrict__ f_b,
    const float* __restrict__ f_m, const float* __restrict__ f_s,
    const float* __restrict__ Amat, float* __restrict__ out) {
  int bn = blockIdx.x;            // b*N + n
  int b  = bn >> 7;
  int n  = bn & 127;
  int t  = threadIdx.x;
  int g  = t >> 6;                // wave 0..3 owns m slice [g*32, g*32+32)
  int lane = t & 63;              // owns d4 = lane*4 .. +3

  __shared__ float a_lds[N_];
  __shared__ float4 red[3][64];

  if (t < N_) a_lds[t] = Amat[(size_t)bn * N_ + t];
  __syncthreads();

  const float4* fs4p   = (const float4*)(f_s + (size_t)b * D_);
  float4 fs4 = fs4p[lane];
  const float4* fmbase = (const float4*)(f_m + (size_t)bn * N_ * D_);
  const float4* fbbase = (const float4*)(f_b + (size_t)b * N_ * D_);

  float4 acc = make_float4(0.f, 0.f, 0.f, 0.f);
#pragma unroll 4
  for (int i = 0; i < 32; ++i) {
    int m = g * 32 + i;
    float a = a_lds[m];
    float4 fm = fmbase[(size_t)m * (D_ / 4) + lane];
    float4 fb = fbbase[(size_t)m * (D_ / 4) + lane];
    float sx = __fdividef(1.f, 1.f + __expf(-fm.x * fs4.x));
    float sy = __fdividef(1.f, 1.f + __expf(-fm.y * fs4.y));
    float sz = __fdividef(1.f, 1.f + __expf(-fm.z * fs4.z));
    float sw = __fdividef(1.f, 1.f + __expf(-fm.w * fs4.w));
    acc.x += a * (fb.x + sx * fm.x);
    acc.y += a * (fb.y + sy * fm.y);
    acc.z += a * (fb.z + sz * fm.z);
    acc.w += a * (fb.w + sw * fm.w);
  }

  if (g > 0) red[g - 1][lane] = acc;
  __syncthreads();
  if (g == 0) {
#pragma unroll
    for (int j = 0; j < 3; ++j) {
      float4 r4 = red[j][lane];
      acc.x += r4.x; acc.y += r4.y; acc.z += r4.z; acc.w += r4.w;
    }
    float4 fbn = fbbase[(size_t)n * (D_ / 4) + lane];
    float4 o;
    o.x = fbn.x + acc.x;
    o.y = fbn.y + acc.y;
    o.z = fbn.z + acc.z;
    o.w = fbn.w + acc.w;
    ((float4*)out)[(size_t)bn * (D_ / 4) + lane] = o;
  }
}

extern "C" void kernel_launch(void* const* d_in, const int* in_sizes, int n_in,
                              void* d_out, int out_size, void* d_ws, size_t ws_size,
                              hipStream_t stream) {
  const float* f_b   = (const float*)d_in[0];
  const float* f_w   = (const float*)d_in[1];
  const float* f_s   = (const float*)d_in[2];
  const float* f_m   = (const float*)d_in[3];
  const float* qmask = (const float*)d_in[4];
  const float* lmask = (const float*)d_in[5];
  const float* Wq    = (const float*)d_in[6];
  const float* bq    = (const float*)d_in[7];
  const float* Wk    = (const float*)d_in[8];
  const float* bk    = (const float*)d_in[9];
  float* out = (float*)d_out;

  float* ws   = (float*)d_ws;
  float* kmat = ws;                       // 240*256      = 61440 floats
  float* fbq  = ws + 65536;               // 1024*256     = 262144 floats
  float* Amat = ws + 65536 + 262144;      // 8*128*128    = 131072 floats

  hipLaunchKernelGGL(k_proj, dim3(B_ * L_), dim3(256), 0, stream, f_w, Wk, bk, kmat);
  hipLaunchKernelGGL(qk_fbq, dim3(B_ * N_ / ROWS), dim3(256), 0, stream,
                     f_b, f_w, f_s, qmask, lmask, Wq, bq, kmat, fbq);
  hipLaunchKernelGGL(a_soft, dim3(B_ * N_ / NR), dim3(256), 0, stream, fbq, lmask, Amat);
  hipLaunchKernelGGL(final_k, dim3(B_ * N_), dim3(256), 0, stream, f_b, f_m, f_s, Amat, out);
}

// Round 2
// 73.883 us; speedup vs baseline: 1.2033x; 1.2033x over previous
//
#include <hip/hip_runtime.h>
#include <math.h>

#define B_ 8
#define N_ 128
#define L_ 30
#define D_ 256
#define NEGV -1000000000.0f
#define SCALE 0.0625f   // 1/sqrt(256)
#define ROWS 4

// ---------------- Kernel 1: k = f_w @ Wk^T + bk  (B*L rows) ----------------
__global__ __launch_bounds__(256) void k_proj(const float* __restrict__ f_w,
    const float* __restrict__ Wk, const float* __restrict__ bk,
    float* __restrict__ k_out) {
  int bl = blockIdx.x;          // b*L + l
  int d  = threadIdx.x;         // 0..255
  __shared__ float fw[D_];
  fw[d] = f_w[bl * D_ + d];
  __syncthreads();
  const float4* wrow = (const float4*)(Wk + (size_t)d * D_);
  float acc = 0.f;
#pragma unroll 8
  for (int j = 0; j < D_ / 4; ++j) {
    float4 w = wrow[j];
    acc += w.x * fw[4*j+0] + w.y * fw[4*j+1] + w.z * fw[4*j+2] + w.w * fw[4*j+3];
  }
  k_out[bl * D_ + d] = acc + bk[d];
}

// ---- Kernel 2: q-proj + aw softmax (over L) + f_baq + f_bq, 4 n-rows/block ----
__global__ __launch_bounds__(256) void qk_fbq(const float* __restrict__ f_b,
    const float* __restrict__ f_w, const float* __restrict__ f_s,
    const float* __restrict__ qmask, const float* __restrict__ lmask,
    const float* __restrict__ Wq, const float* __restrict__ bq,
    const float* __restrict__ kmat, float* __restrict__ f_bq) {
  int blk = blockIdx.x;
  int b   = blk / (N_ / ROWS);
  int n0  = (blk % (N_ / ROWS)) * ROWS;
  int d   = threadIdx.x;

  __shared__ float fb[ROWS][D_];        // broadcast reads only
  __shared__ float qs[ROWS][D_ + 1];    // padded
  __shared__ float aw[ROWS][L_ + 2];

  for (int r = 0; r < ROWS; ++r)
    fb[r][d] = f_b[(size_t)(b * N_ + n0 + r) * D_ + d];
  __syncthreads();

  // q[r][d] = f_b[r] . Wq[d,:] + bq[d]
  float qacc[ROWS];
#pragma unroll
  for (int r = 0; r < ROWS; ++r) qacc[r] = 0.f;
  const float4* wrow = (const float4*)(Wq + (size_t)d * D_);
  for (int j = 0; j < D_ / 4; ++j) {
    float4 w = wrow[j];
#pragma unroll
    for (int r = 0; r < ROWS; ++r)
      qacc[r] += w.x*fb[r][4*j] + w.y*fb[r][4*j+1] + w.z*fb[r][4*j+2] + w.w*fb[r][4*j+3];
  }
  float bqd = bq[d];
#pragma unroll
  for (int r = 0; r < ROWS; ++r) qs[r][d] = qacc[r] + bqd;
  __syncthreads();

  // aw[r][l] = (q[r] . k[l]) * scale, with query mask
  if (d < ROWS * L_) {
    int r = d / L_, l = d % L_;
    const float4* krow = (const float4*)(kmat + (size_t)(b * L_ + l) * D_);
    float acc = 0.f;
    for (int j = 0; j < D_ / 4; ++j) {
      float4 kv = krow[j];
      acc += kv.x*qs[r][4*j] + kv.y*qs[r][4*j+1] + kv.z*qs[r][4*j+2] + kv.w*qs[r][4*j+3];
    }
    float qm = qmask[b * L_ + l];
    aw[r][l] = (qm == 0.f) ? NEGV : acc * SCALE * qm;
  }
  __syncthreads();

  // per-row softmax over L=30 (serial, 4 threads — tiny)
  if (d < ROWS) {
    int r = d;
    float mx = -1e30f;
    for (int l = 0; l < L_; ++l) mx = fmaxf(mx, aw[r][l]);
    float s = 0.f;
    for (int l = 0; l < L_; ++l) { float e = __expf(aw[r][l] - mx); aw[r][l] = e; s += e; }
    float inv = 1.f / s;
    for (int l = 0; l < L_; ++l) aw[r][l] *= inv;
  }
  __syncthreads();

  // f_baq[r][d] = sum_l aw[r][l] * f_w[l][d];  f_bq = f_b * (f_baq*lm + f_s)
  float facc[ROWS];
#pragma unroll
  for (int r = 0; r < ROWS; ++r) facc[r] = 0.f;
  for (int l = 0; l < L_; ++l) {
    float fwv = f_w[(size_t)(b * L_ + l) * D_ + d];
#pragma unroll
    for (int r = 0; r < ROWS; ++r) facc[r] += aw[r][l] * fwv;
  }
  float fsd = f_s[b * D_ + d];
#pragma unroll
  for (int r = 0; r < ROWS; ++r) {
    float lm = lmask[b * N_ + n0 + r];
    f_bq[(size_t)(b * N_ + n0 + r) * D_ + d] = fb[r][d] * (facc[r] * lm + fsd);
  }
}

// ---- Kernel 3 (fused): A-row softmax + stream f_m:
//      out[n,:] = f_b[n] + sum_m A[n,m]*(f_b[m] + sigmoid(f_m*f_s)*f_m) ----
__global__ __launch_bounds__(512) void fused_final(const float* __restrict__ f_b,
    const float* __restrict__ f_m, const float* __restrict__ f_s,
    const float* __restrict__ lmask, const float* __restrict__ f_bq,
    float* __restrict__ out) {
  int bn = blockIdx.x;            // b*N + n
  int b  = bn >> 7;
  int n  = bn & 127;
  int t  = threadIdx.x;           // 0..511
  int wave = t >> 6;              // 0..7
  int lane = t & 63;

  __shared__ float qn[D_];
  __shared__ float part[N_][5];   // [m][quarter], padded
  __shared__ float a_lds[N_];
  __shared__ float sm[8];
  __shared__ float4 red[7][64];

  // ---- Phase A: A-row = softmax(f_bq[n] . f_bq[m] * scale, masked) * lmask[n]
  if (t < D_) qn[t] = f_bq[(size_t)bn * D_ + t];
  __syncthreads();

  {
    int m = t >> 2, q = t & 3;    // 4 threads per m-row, 64 elems each
    const float4* rowp = (const float4*)(f_bq + (size_t)(b * N_ + m) * D_ + q * 64);
    const float4* qp   = (const float4*)(qn + q * 64);
    float acc = 0.f;
#pragma unroll
    for (int j = 0; j < 16; ++j) {
      float4 v = rowp[j]; float4 qv = qp[j];
      acc += v.x*qv.x + v.y*qv.y + v.z*qv.z + v.w*qv.w;
    }
    part[m][q] = acc;
  }
  __syncthreads();

  float myval = NEGV;
  if (t < N_) {
    float s = part[t][0] + part[t][1] + part[t][2] + part[t][3];
    float lm = lmask[b * N_ + t];
    myval = (lm == 0.f) ? NEGV : s * SCALE * lm;
  }
  if (t < N_) {
    float mx = myval;
#pragma unroll
    for (int off = 32; off >= 1; off >>= 1) mx = fmaxf(mx, __shfl_xor(mx, off));
    if (lane == 0) sm[wave] = mx;
  }
  __syncthreads();
  float e = 0.f;
  if (t < N_) {
    float gmax = fmaxf(sm[0], sm[1]);
    e = __expf(myval - gmax);
    float ssum = e;
#pragma unroll
    for (int off = 32; off >= 1; off >>= 1) ssum += __shfl_xor(ssum, off);
    if (lane == 0) sm[4 + wave] = ssum;
  }
  __syncthreads();
  if (t < N_) {
    float tot = sm[4] + sm[5];
    float fbm = lmask[b * N_ + n];
    a_lds[t] = e * (fbm / tot);
  }
  __syncthreads();

  // ---- Phase B: stream f_m. wave handles m in [wave*16, wave*16+16).
  float4 fs4 = ((const float4*)(f_s + (size_t)b * D_))[lane];
  const float4* fmbase = (const float4*)(f_m + (size_t)bn * N_ * D_);
  const float4* fbbase = (const float4*)(f_b + (size_t)b * N_ * D_);

  float4 acc = make_float4(0.f, 0.f, 0.f, 0.f);
  int m0 = wave * 16;
#pragma unroll 4
  for (int i = 0; i < 16; ++i) {
    int m = m0 + i;
    float a = a_lds[m];
    float4 fm = fmbase[(size_t)m * (D_ / 4) + lane];
    float4 fb = fbbase[(size_t)m * (D_ / 4) + lane];
    float sx = __fdividef(1.f, 1.f + __expf(-fm.x * fs4.x));
    float sy = __fdividef(1.f, 1.f + __expf(-fm.y * fs4.y));
    float sz = __fdividef(1.f, 1.f + __expf(-fm.z * fs4.z));
    float sw = __fdividef(1.f, 1.f + __expf(-fm.w * fs4.w));
    acc.x += a * (fb.x + sx * fm.x);
    acc.y += a * (fb.y + sy * fm.y);
    acc.z += a * (fb.z + sz * fm.z);
    acc.w += a * (fb.w + sw * fm.w);
  }

  if (wave > 0) red[wave - 1][lane] = acc;
  __syncthreads();
  if (wave == 0) {
#pragma unroll
    for (int j = 0; j < 7; ++j) {
      float4 r4 = red[j][lane];
      acc.x += r4.x; acc.y += r4.y; acc.z += r4.z; acc.w += r4.w;
    }
    float4 fbn = fbbase[(size_t)n * (D_ / 4) + lane];
    float4 o;
    o.x = fbn.x + acc.x;
    o.y = fbn.y + acc.y;
    o.z = fbn.z + acc.z;
    o.w = fbn.w + acc.w;
    ((float4*)out)[(size_t)bn * (D_ / 4) + lane] = o;
  }
}

extern "C" void kernel_launch(void* const* d_in, const int* in_sizes, int n_in,
                              void* d_out, int out_size, void* d_ws, size_t ws_size,
                              hipStream_t stream) {
  const float* f_b   = (const float*)d_in[0];
  const float* f_w   = (const float*)d_in[1];
  const float* f_s   = (const float*)d_in[2];
  const float* f_m   = (const float*)d_in[3];
  const float* qmask = (const float*)d_in[4];
  const float* lmask = (const float*)d_in[5];
  const float* Wq    = (const float*)d_in[6];
  const float* bq    = (const float*)d_in[7];
  const float* Wk    = (const float*)d_in[8];
  const float* bk    = (const float*)d_in[9];
  float* out = (float*)d_out;

  float* ws   = (float*)d_ws;
  float* kmat = ws;                       // 240*256      = 61440 floats
  float* fbq  = ws + 65536;               // 1024*256     = 262144 floats

  hipLaunchKernelGGL(k_proj, dim3(B_ * L_), dim3(256), 0, stream, f_w, Wk, bk, kmat);
  hipLaunchKernelGGL(qk_fbq, dim3(B_ * N_ / ROWS), dim3(256), 0, stream,
                     f_b, f_w, f_s, qmask, lmask, Wq, bq, kmat, fbq);
  hipLaunchKernelGGL(fused_final, dim3(B_ * N_), dim3(512), 0, stream,
                     f_b, f_m, f_s, lmask, fbq, out);
}